// Round 8
// baseline (236.000 us; speedup 1.0000x reference)
//
#include <hip/hip_runtime.h>

#define BATCH 8
#define NCLS 21
#define H 512
#define W 512
#define IGNORE_INDEX 255
#define HW (H * W)
#define NPIX (BATCH * HW)
#define NBLK 1024   // BATCH * (H/4): each block = one batch image, 4 rows

typedef float vfloat4 __attribute__((ext_vector_type(4)));

// Boundary bits for pixels (h, w..w+3): bit j set iff bd(h, w+j).
// bd(h,w) = OR over batch, OR over cols w-1..w+1 of
//           [3-row column (h-1,h,h+1) not all equal].  (R7-validated)
__device__ __forceinline__ unsigned boundary4(const int* __restrict__ t,
                                              int h, int w) {
    unsigned r = 0;
    if (h > 0 && h < H - 1) {
        int offL = (w == 0) ? 0 : -1;        // clamp: feeds only bit0 (zeroed)
        int offR = (w == W - 4) ? 3 : 4;     // clamp: feeds only bit3 (zeroed)
        #pragma unroll 1
        for (int bb = 0; bb < BATCH; ++bb) {
            const int* rm = t + bb * HW + h * W + w;
            const int* ra = rm - W;
            const int* rz = rm + W;
            int4 a4 = *(const int4*)ra;
            int4 m4 = *(const int4*)rm;
            int4 z4 = *(const int4*)rz;
            int aL = ra[offL], mL = rm[offL], zL = rz[offL];
            int aR = ra[offR], mR = rm[offR], zR = rz[offR];
            unsigned cdL = (unsigned)((aL != mL) | (mL != zL));
            unsigned cd0 = (unsigned)((a4.x != m4.x) | (m4.x != z4.x));
            unsigned cd1 = (unsigned)((a4.y != m4.y) | (m4.y != z4.y));
            unsigned cd2 = (unsigned)((a4.z != m4.z) | (m4.z != z4.z));
            unsigned cd3 = (unsigned)((a4.w != m4.w) | (m4.w != z4.w));
            unsigned cdR = (unsigned)((aR != mR) | (mR != zR));
            r |= (cdL | cd0 | cd1) | ((cd0 | cd1 | cd2) << 1) |
                 ((cd1 | cd2 | cd3) << 2) | ((cd2 | cd3 | cdR) << 3);
            if (r == 0xFu) break;            // ~always at bb=0 (random targets)
        }
        if (w == 0) r &= ~1u;
        if (w == W - 4) r &= ~8u;
    }
    return r;
}

// Block = (batch b, row-group of 4 rows). Per channel the block reads one
// CONTIGUOUS 8 KB segment and walks the 21 channels sequentially with a
// 1-channel prefetch pipeline -> ~2 active DRAM streams per block instead
// of 21 (R7 theory: ~21k concurrent 1KB-granular streams capped us at
// ~2.7 TB/s). Thread: 8 pixels = quad at (h0, w) + quad at (h0+2, w).
// nt on logit loads (R4/R7 vs R5/R6 A/B: worth ~10 us).
__global__ __launch_bounds__(256)
void fused_kernel(const float* __restrict__ x, const int* __restrict__ t,
                  float* __restrict__ partial) {
    int blk = blockIdx.x;
    int b = blk >> 7;            // / (H/4)
    int hq = blk & 127;
    int i = threadIdx.x;
    int h0 = (hq << 2) + (i >> 7);   // quad A row; quad B row = h0 + 2
    int w = (i & 127) << 2;          // 0..508, multiple of 4

    int hw0 = (h0 << 9) + w;
    int hw1 = hw0 + 2 * W;

    // boundary + targets (L2-resident small data)
    unsigned bdA = boundary4(t, h0, w);
    unsigned bdB = boundary4(t, h0 + 2, w);
    int4 tgA = *(const int4*)(t + b * HW + hw0);
    int4 tgB = *(const int4*)(t + b * HW + hw1);

    bool vA0 = tgA.x != IGNORE_INDEX, vA1 = tgA.y != IGNORE_INDEX;
    bool vA2 = tgA.z != IGNORE_INDEX, vA3 = tgA.w != IGNORE_INDEX;
    bool vB0 = tgB.x != IGNORE_INDEX, vB1 = tgB.y != IGNORE_INDEX;
    bool vB2 = tgB.z != IGNORE_INDEX, vB3 = tgB.w != IGNORE_INDEX;
    int sA0 = vA0 ? tgA.x : 0, sA1 = vA1 ? tgA.y : 0;
    int sA2 = vA2 ? tgA.z : 0, sA3 = vA3 ? tgA.w : 0;
    int sB0 = vB0 ? tgB.x : 0, sB1 = vB1 ? tgB.y : 0;
    int sB2 = vB2 ? tgB.z : 0, sB3 = vB3 ? tgB.w : 0;

    const float* p0 = x + (size_t)b * NCLS * HW + hw0;
    const float* p1 = x + (size_t)b * NCLS * HW + hw1;

    // channel pipeline: prefetch c+1 while consuming c
    vfloat4 a0 = __builtin_nontemporal_load((const vfloat4*)p0);
    vfloat4 a1 = __builtin_nontemporal_load((const vfloat4*)p1);

    float eA0 = 0.f, eA1 = 0.f, eA2 = 0.f, eA3 = 0.f;
    float eB0 = 0.f, eB1 = 0.f, eB2 = 0.f, eB3 = 0.f;
    float xA0 = 0.f, xA1 = 0.f, xA2 = 0.f, xA3 = 0.f;
    float xB0 = 0.f, xB1 = 0.f, xB2 = 0.f, xB3 = 0.f;

    #pragma unroll
    for (int c = 0; c < NCLS; ++c) {
        vfloat4 n0, n1;
        if (c + 1 < NCLS) {
            n0 = __builtin_nontemporal_load((const vfloat4*)(p0 + (size_t)(c + 1) * HW));
            n1 = __builtin_nontemporal_load((const vfloat4*)(p1 + (size_t)(c + 1) * HW));
        }
        eA0 += __expf(a0.x); if (c == sA0) xA0 = a0.x;
        eA1 += __expf(a0.y); if (c == sA1) xA1 = a0.y;
        eA2 += __expf(a0.z); if (c == sA2) xA2 = a0.z;
        eA3 += __expf(a0.w); if (c == sA3) xA3 = a0.w;
        eB0 += __expf(a1.x); if (c == sB0) xB0 = a1.x;
        eB1 += __expf(a1.y); if (c == sB1) xB1 = a1.y;
        eB2 += __expf(a1.z); if (c == sB2) xB2 = a1.z;
        eB3 += __expf(a1.w); if (c == sB3) xB3 = a1.w;
        a0 = n0; a1 = n1;
    }

    float local =
        (vA0 ? (__logf(eA0) - xA0) : 0.f) * (1.f + 2.f * (float)(bdA & 1u)) +
        (vA1 ? (__logf(eA1) - xA1) : 0.f) * (1.f + 2.f * (float)((bdA >> 1) & 1u)) +
        (vA2 ? (__logf(eA2) - xA2) : 0.f) * (1.f + 2.f * (float)((bdA >> 2) & 1u)) +
        (vA3 ? (__logf(eA3) - xA3) : 0.f) * (1.f + 2.f * (float)((bdA >> 3) & 1u)) +
        (vB0 ? (__logf(eB0) - xB0) : 0.f) * (1.f + 2.f * (float)(bdB & 1u)) +
        (vB1 ? (__logf(eB1) - xB1) : 0.f) * (1.f + 2.f * (float)((bdB >> 1) & 1u)) +
        (vB2 ? (__logf(eB2) - xB2) : 0.f) * (1.f + 2.f * (float)((bdB >> 2) & 1u)) +
        (vB3 ? (__logf(eB3) - xB3) : 0.f) * (1.f + 2.f * (float)((bdB >> 3) & 1u));

    #pragma unroll
    for (int off = 32; off > 0; off >>= 1)
        local += __shfl_down(local, off, 64);

    __shared__ float smem[4];
    int lane = threadIdx.x & 63;
    int wave = threadIdx.x >> 6;
    if (lane == 0) smem[wave] = local;
    __syncthreads();
    if (threadIdx.x == 0)
        partial[blockIdx.x] = smem[0] + smem[1] + smem[2] + smem[3];
}

__global__ void reduce_kernel(const float* __restrict__ partial,
                              float* __restrict__ out) {
    float s = 0.0f;
    for (int i = threadIdx.x; i < NBLK; i += 256) s += partial[i];
    #pragma unroll
    for (int off = 32; off > 0; off >>= 1)
        s += __shfl_down(s, off, 64);
    __shared__ float smem[4];
    int lane = threadIdx.x & 63;
    int wave = threadIdx.x >> 6;
    if (lane == 0) smem[wave] = s;
    __syncthreads();
    if (threadIdx.x == 0)
        out[0] = (smem[0] + smem[1] + smem[2] + smem[3]) * (1.0f / (float)NPIX);
}

extern "C" void kernel_launch(void* const* d_in, const int* in_sizes, int n_in,
                              void* d_out, int out_size, void* d_ws, size_t ws_size,
                              hipStream_t stream) {
    const float* x = (const float*)d_in[0];
    const int* t = (const int*)d_in[1];
    float* out = (float*)d_out;
    float* partial = (float*)d_ws;  // NBLK floats = 4 KB

    fused_kernel<<<NBLK, 256, 0, stream>>>(x, t, partial);
    reduce_kernel<<<1, 256, 0, stream>>>(partial, out);
}